// Round 7
// baseline (271.151 us; speedup 1.0000x reference)
//
#include <hip/hip_runtime.h>

#define N_NODES 100000
#define C_DIM 128
#define E_EDGES 800000
#define V_OUT 50000
#define EN (E_EDGES + N_NODES)      /* 900000  per-layer CSR entries */
#define M2 (2 * N_NODES)
#define EN2 (2 * EN)                /* 1800000 */

#define BSHIFT 9                    /* 512 nodes per coarse bucket */
#define NBUCK_L ((N_NODES + 511) >> 9)   /* 196 per layer */
#define NBUCK2 (2 * NBUCK_L)             /* 392 */
#define CAP 8192                    /* slab capacity; avg fill ~4608 */
#define P1_CHUNK 4096
#define P1_PER_T (P1_CHUNK / 256)   /* 16 */
#define NCHUNK ((EN2 + P1_CHUNK - 1) / P1_CHUNK) /* 440 */
#define VFLAG_BLKS ((V_OUT + 255) / 256)         /* 196 */

#define XPAD 136                    /* LDS row stride (ushorts): 272B, 2-way banks */
#define LDS_E 768                   /* staged edges per 16-node block; mean 144, +15 sigma safe */

typedef unsigned int uint;
typedef unsigned short ushort;
typedef __attribute__((ext_vector_type(8))) short bf16x8;
typedef __attribute__((ext_vector_type(4))) float f32x4;

static __device__ __forceinline__ ushort f2bf(float f) {
    uint u = __float_as_uint(f);
    u += 0x7fffu + ((u >> 16) & 1);   // round-to-nearest-even
    return (ushort)(u >> 16);
}

// ---------------------------------------------------------------------------
// MFMA GEMM, streaming-X: W in LDS (34.8 KB only -> 4 blocks/CU, 16 waves/CU,
// 2x the occupancy of the staged versions). A-fragments load STRAIGHT from
// global (per-wave: 16 rows x 256B contiguous, fully coalesced) -- no X
// staging, no double buffer, 3 barriers per BLOCK (not per chunk).
// After MFMA, ws is dead -> reused as transpose scratch for the coalesced
// 16B hb store. acc carried as packed bf16 in 16 regs between phases.
// ---------------------------------------------------------------------------
template <int IN_F32>
__global__ __launch_bounds__(256, 4) void gemm_mfma(
    const void* __restrict__ xin, const float* __restrict__ W,
    const float* __restrict__ att_s, const float* __restrict__ att_d,
    ushort* __restrict__ hb, float* __restrict__ a_s, float* __restrict__ a_d)
{
    __shared__ ushort ws[128 * XPAD];   // 34.8 KB: W for MFMA phase, then scratch
    const int tid = threadIdx.x;

    // ---- stage W (fp32 -> bf16): thread t -> row t>>1, half t&1 ----------
    {
        const int row = tid >> 1, half = tid & 1;
        const float* src = W + row * 128 + half * 64;
        ushort* dst = &ws[row * XPAD + half * 64];
        #pragma unroll
        for (int i = 0; i < 8; ++i) {
            float4 u = *reinterpret_cast<const float4*>(src + i * 8);
            float4 v = *reinterpret_cast<const float4*>(src + i * 8 + 4);
            uint4 pk;
            pk.x = (uint)f2bf(u.x) | ((uint)f2bf(u.y) << 16);
            pk.y = (uint)f2bf(u.z) | ((uint)f2bf(u.w) << 16);
            pk.z = (uint)f2bf(v.x) | ((uint)f2bf(v.y) << 16);
            pk.w = (uint)f2bf(v.z) | ((uint)f2bf(v.w) << 16);
            *reinterpret_cast<uint4*>(dst + i * 8) = pk;
        }
    }

    const int lane = tid & 63, wv = tid >> 6;
    const int m = lane & 15, quad = lane >> 4;
    const int nb = blockIdx.x * 64;
    const int n0 = nb + wv * 16;
    const long xrow = min((long)(n0 + m), (long)N_NODES - 1);

    // ---- A-fragments straight from global (coalesced within the wave) ----
    bf16x8 a[4];
    if (IN_F32) {
        const float* src = (const float*)xin + xrow * 128 + quad * 8;
        #pragma unroll
        for (int ki = 0; ki < 4; ++ki) {
            float4 u = *reinterpret_cast<const float4*>(src + ki * 32);
            float4 v = *reinterpret_cast<const float4*>(src + ki * 32 + 4);
            uint4 pk;
            pk.x = (uint)f2bf(u.x) | ((uint)f2bf(u.y) << 16);
            pk.y = (uint)f2bf(u.z) | ((uint)f2bf(u.w) << 16);
            pk.z = (uint)f2bf(v.x) | ((uint)f2bf(v.y) << 16);
            pk.w = (uint)f2bf(v.z) | ((uint)f2bf(v.w) << 16);
            a[ki] = *reinterpret_cast<bf16x8*>(&pk);
        }
    } else {
        const ushort* src = (const ushort*)xin + xrow * 128 + quad * 8;
        #pragma unroll
        for (int ki = 0; ki < 4; ++ki)
            a[ki] = *reinterpret_cast<const bf16x8*>(src + ki * 32);
    }
    __syncthreads();                  // W staged

    // ---- MFMA phase: 8 column-tiles, acc -> packed bf16 in regs ----------
    float ps[4] = {0, 0, 0, 0}, pd[4] = {0, 0, 0, 0};
    uint2 packed[8];
    #pragma unroll
    for (int ct = 0; ct < 8; ++ct) {
        const int cc = ct * 16 + m;
        f32x4 acc = {0.f, 0.f, 0.f, 0.f};
        #pragma unroll
        for (int ki = 0; ki < 4; ++ki) {
            bf16x8 b = *reinterpret_cast<const bf16x8*>(&ws[cc * XPAD + quad * 8 + ki * 32]);
            acc = __builtin_amdgcn_mfma_f32_16x16x32_bf16(a[ki], b, acc, 0, 0, 0);
        }
        const float asc = att_s[cc], adc = att_d[cc];
        #pragma unroll
        for (int r = 0; r < 4; ++r) {
            ps[r] = fmaf(acc[r], asc, ps[r]);
            pd[r] = fmaf(acc[r], adc, pd[r]);
        }
        packed[ct].x = (uint)f2bf(acc[0]) | ((uint)f2bf(acc[1]) << 16);
        packed[ct].y = (uint)f2bf(acc[2]) | ((uint)f2bf(acc[3]) << 16);
    }
    __syncthreads();                  // all ws B-reads done -> ws reusable

    // ---- transpose through ws rows 0..63: row wv*16+quad*4+r, col ct*16+m -
    {
        const int rowb = (wv * 16 + quad * 4) * XPAD + m;
        #pragma unroll
        for (int ct = 0; ct < 8; ++ct) {
            ws[rowb            + ct * 16] = (ushort)(packed[ct].x);
            ws[rowb +     XPAD + ct * 16] = (ushort)(packed[ct].x >> 16);
            ws[rowb + 2 * XPAD + ct * 16] = (ushort)(packed[ct].y);
            ws[rowb + 3 * XPAD + ct * 16] = (ushort)(packed[ct].y >> 16);
        }
    }
    __syncthreads();                  // transpose complete

    // ---- coalesced hb store: wave covers 4 rows x 256B contiguous --------
    {
        const int sub = tid & 15, rb = tid >> 4;
        #pragma unroll
        for (int i = 0; i < 4; ++i) {
            const int rl = rb + i * 16;
            const int node = nb + rl;
            uint4 v = *reinterpret_cast<const uint4*>(&ws[rl * XPAD + sub * 8]);
            if (node < N_NODES)
                *reinterpret_cast<uint4*>(hb + (long)node * 128 + sub * 8) = v;
        }
    }
    // ---- a_s / a_d shuffle reduce ----------------------------------------
    #pragma unroll
    for (int r = 0; r < 4; ++r) {
        float s = ps[r], d = pd[r];
        #pragma unroll
        for (int x = 1; x < 16; x <<= 1) { s += __shfl_xor(s, x); d += __shfl_xor(d, x); }
        const int node = n0 + quad * 4 + r;
        if (m == 0 && node < N_NODES) { a_s[node] = s; a_d[node] = d; }
    }
}

// ---------------------------------------------------------------------------
// CSR build pass 1 + inverse-output-list build fused (unchanged from R6).
// ---------------------------------------------------------------------------
__global__ __launch_bounds__(256) void partition_kernel(
    const int* __restrict__ e1, const int* __restrict__ e2,
    int* __restrict__ cursor, uint* __restrict__ slab,
    const int* __restrict__ idxm, int* __restrict__ head, int* __restrict__ nextp)
{
    __shared__ int cnt[NBUCK2];
    __shared__ int basearr[NBUCK2];
    const int tid = threadIdx.x;
    const int blk = blockIdx.x;
    if (blk >= NCHUNK) {
        int v = (blk - NCHUNK) * 256 + tid;
        if (v < V_OUT) {
            int n = idxm[v];
            int old = atomicExch(&head[n], v);   // lock-free list push
            nextp[v] = old;
        }
        return;
    }
    for (int i = tid; i < NBUCK2; i += 256) cnt[i] = 0;
    __syncthreads();

    const int e0 = blk * P1_CHUNK;
    uint ent[P1_PER_T];
    int  bkt[P1_PER_T];
    #pragma unroll
    for (int i = 0; i < P1_PER_T; ++i) {
        int e = e0 + i * 256 + tid;
        bkt[i] = -1;
        if (e < EN2) {
            int src, dst, lb;
            if (e < EN) {
                if (e < E_EDGES) { src = e1[e]; dst = e1[E_EDGES + e]; }
                else             { src = dst = e - E_EDGES; }
                lb = 0;
            } else {
                int f = e - EN;
                if (f < E_EDGES) { src = e2[f]; dst = e2[E_EDGES + f]; }
                else             { src = dst = f - E_EDGES; }
                lb = NBUCK_L;
            }
            bkt[i] = lb + (dst >> BSHIFT);
            ent[i] = (uint)src | ((uint)(dst & 511) << 17);
            atomicAdd(&cnt[bkt[i]], 1);
        }
    }
    __syncthreads();
    for (int b = tid; b < NBUCK2; b += 256) {
        int c = cnt[b];
        basearr[b] = (c > 0) ? atomicAdd(&cursor[b], c) : 0;
        cnt[b] = 0;                       // reuse as rank counter
    }
    __syncthreads();
    #pragma unroll
    for (int i = 0; i < P1_PER_T; ++i) {
        if (bkt[i] >= 0) {
            int r = basearr[bkt[i]] + atomicAdd(&cnt[bkt[i]], 1);
            if (r < CAP) slab[(long)bkt[i] * CAP + r] = ent[i];
        }
    }
}

// ---------------------------------------------------------------------------
// CSR build, pass 2 (unchanged): one workgroup per bucket -> local CSR.
// ---------------------------------------------------------------------------
__global__ __launch_bounds__(256) void local_csr(
    const uint* __restrict__ slab, const int* __restrict__ cursor,
    int* __restrict__ offs, uint* __restrict__ esrc)
{
    __shared__ uint ent[CAP];         // 32 KB
    __shared__ int deg[512];
    __shared__ int excl[512];
    __shared__ int sbase;
    const int b = blockIdx.x;
    const int tid = threadIdx.x;
    const int cnt = min(cursor[b], CAP);
    const int layer = (b >= NBUCK_L);
    const int node0 = (b - layer * NBUCK_L) << BSHIFT;
    const int obase = layer * N_NODES;
    const int nodes_n = min(512, N_NODES - node0);

    for (int i = tid; i < 512; i += 256) deg[i] = 0;
    if (tid < 64) {                   // wave-0: base = sum(cursor[0..b))
        int s = 0;
        #pragma unroll
        for (int k = 0; k < 7; ++k) {
            int idx = tid + 64 * k;
            if (idx < b) s += cursor[idx];
        }
        #pragma unroll
        for (int d = 32; d > 0; d >>= 1) s += __shfl_down(s, d);
        if (tid == 0) sbase = s;
    }
    __syncthreads();
    const int base = sbase;

    for (int i = tid; i < cnt; i += 256) {
        uint v = slab[(long)b * CAP + i];
        ent[i] = v;
        atomicAdd(&deg[v >> 17], 1);
    }
    __syncthreads();
    if (tid < 64) {                   // wave-0 scan of deg[512], 8 per lane
        int v8[8]; int s = 0;
        #pragma unroll
        for (int i = 0; i < 8; ++i) { v8[i] = deg[tid * 8 + i]; s += v8[i]; }
        int incl = s;
        #pragma unroll
        for (int d = 1; d < 64; d <<= 1) {
            int t = __shfl_up(incl, d);
            if (tid >= d) incl += t;
        }
        int e = incl - s;
        #pragma unroll
        for (int i = 0; i < 8; ++i) { excl[tid * 8 + i] = e; e += v8[i]; }
    }
    __syncthreads();
    for (int i = tid; i < nodes_n; i += 256)
        offs[obase + node0 + i] = base + excl[i];
    for (int i = tid; i < 512; i += 256) deg[i] = 0;   // reuse as rank ctr
    if (tid == 0 && node0 + 512 >= N_NODES)
        offs[obase + N_NODES] = base + cnt;            // layer sentinel
    __syncthreads();
    for (int i = tid; i < cnt; i += 256) {
        uint v = ent[i];
        int dl = v >> 17;
        int r = atomicAdd(&deg[dl], 1);
        esrc[base + excl[dl] + r] = v;                 // packed src|dl<<17
    }
}

// ---------------------------------------------------------------------------
// Softmax aggregation (unchanged from R6 — the measured control at 43.4 us).
// ---------------------------------------------------------------------------
template <int MODE>
__global__ __launch_bounds__(256) void aggregate(
    const ushort* __restrict__ hb, const float* __restrict__ a_s,
    const float* __restrict__ a_d, const float* __restrict__ bias,
    const int* __restrict__ offs, const uint* __restrict__ esrc,
    const int* __restrict__ head, const int* __restrict__ nextp,
    void* __restrict__ outp, int obase)
{
    __shared__ uint2 ew[LDS_E];       // 6 KB
    const int tid = threadIdx.x;
    const int node0 = blockIdx.x * 16;            // grid = N/16 = 6250
    const int bnode0 = (node0 >> BSHIFT) << BSHIFT;  // bucket's first node (layer-local)
    const int bstart = offs[obase + node0];
    const int bend   = offs[obase + node0 + 16];
    const int nE = bend - bstart;

    // ---- phase 1: stage {v, w} for the block's edges ---------------------
    for (int i = tid; i < min(nE, LDS_E); i += 256) {
        uint v = esrc[bstart + i];
        float w = 0.0f;
        const int d = bnode0 + (v >> 17);
        if (MODE == 0 || head[d] >= 0) {
            float e = a_s[v & 0x1ffff] + a_d[d];
            e = (e >= 0.0f) ? e : 0.2f * e;
            w = __expf(e);
        }
        ew[i] = make_uint2(v, __float_as_uint(w));
    }
    __syncthreads();

    // ---- phase 2: slot loop ----------------------------------------------
    const int wave = tid >> 6;
    const int lane = tid & 63;
    const int slot = lane >> 4;
    const int c16  = lane & 15;
    const int node = node0 + wave * 4 + slot;
    int hv = 0;
    if (MODE == 1) {
        hv = head[node];
        if (hv < 0) return;           // uniform across the slot's 16 lanes
    }

    const int start = offs[obase + node];
    const int end   = offs[obase + node + 1];
    const long coff = (long)(c16 << 3);
    float acc[8] = {0, 0, 0, 0, 0, 0, 0, 0};
    float dsum = 0.0f;

    if (start < end) {
        if (nE <= LDS_E) {
            // fast path: per-edge state from LDS, 4-deep h pipeline
            const int jr = start - bstart, jend = end - bstart;
            const int e1 = jend - 1;
            uint2 p0 = ew[jr];
            uint2 p1 = ew[min(jr + 1, e1)];
            uint2 p2 = ew[min(jr + 2, e1)];
            uint2 p3 = ew[min(jr + 3, e1)];
            uint4 h0 = *reinterpret_cast<const uint4*>(hb + ((long)(p0.x & 0x1ffff) << 7) + coff);
            uint4 h1 = *reinterpret_cast<const uint4*>(hb + ((long)(p1.x & 0x1ffff) << 7) + coff);
            uint4 h2 = *reinterpret_cast<const uint4*>(hb + ((long)(p2.x & 0x1ffff) << 7) + coff);
            uint4 h3 = *reinterpret_cast<const uint4*>(hb + ((long)(p3.x & 0x1ffff) << 7) + coff);
            float w0 = __uint_as_float(p0.y);
            float w1 = __uint_as_float(p1.y);
            float w2 = __uint_as_float(p2.y);
            float w3 = __uint_as_float(p3.y);
            for (int j = jr; j < jend; ++j) {
                uint2 p4 = ew[min(j + 4, e1)];
                uint4 h4 = *reinterpret_cast<const uint4*>(hb + ((long)(p4.x & 0x1ffff) << 7) + coff);
                float w4 = __uint_as_float(p4.y);
                dsum += w0;
                acc[0] = fmaf(w0, __uint_as_float(h0.x << 16),         acc[0]);
                acc[1] = fmaf(w0, __uint_as_float(h0.x & 0xffff0000u), acc[1]);
                acc[2] = fmaf(w0, __uint_as_float(h0.y << 16),         acc[2]);
                acc[3] = fmaf(w0, __uint_as_float(h0.y & 0xffff0000u), acc[3]);
                acc[4] = fmaf(w0, __uint_as_float(h0.z << 16),         acc[4]);
                acc[5] = fmaf(w0, __uint_as_float(h0.z & 0xffff0000u), acc[5]);
                acc[6] = fmaf(w0, __uint_as_float(h0.w << 16),         acc[6]);
                acc[7] = fmaf(w0, __uint_as_float(h0.w & 0xffff0000u), acc[7]);
                w0 = w1; w1 = w2; w2 = w3; w3 = w4;
                h0 = h1; h1 = h2; h2 = h3; h3 = h4;
            }
        } else {
            // slow correct path (never taken in practice)
            const float ad = a_d[node];
            for (int j = start; j < end; ++j) {
                uint v = esrc[j];
                float e = a_s[v & 0x1ffff] + ad;
                e = (e >= 0.0f) ? e : 0.2f * e;
                float w = __expf(e);
                uint4 h = *reinterpret_cast<const uint4*>(hb + ((long)(v & 0x1ffff) << 7) + coff);
                dsum += w;
                acc[0] = fmaf(w, __uint_as_float(h.x << 16),         acc[0]);
                acc[1] = fmaf(w, __uint_as_float(h.x & 0xffff0000u), acc[1]);
                acc[2] = fmaf(w, __uint_as_float(h.y << 16),         acc[2]);
                acc[3] = fmaf(w, __uint_as_float(h.y & 0xffff0000u), acc[3]);
                acc[4] = fmaf(w, __uint_as_float(h.z << 16),         acc[4]);
                acc[5] = fmaf(w, __uint_as_float(h.z & 0xffff0000u), acc[5]);
                acc[6] = fmaf(w, __uint_as_float(h.w << 16),         acc[6]);
                acc[7] = fmaf(w, __uint_as_float(h.w & 0xffff0000u), acc[7]);
            }
        }
    }

    const float inv = 1.0f / (dsum + 1e-16f);
    const int c0 = c16 << 3;
    const float4 b0 = *reinterpret_cast<const float4*>(bias + c0);
    const float4 b1 = *reinterpret_cast<const float4*>(bias + c0 + 4);
    float res[8];
    res[0] = fmaf(acc[0], inv, b0.x);
    res[1] = fmaf(acc[1], inv, b0.y);
    res[2] = fmaf(acc[2], inv, b0.z);
    res[3] = fmaf(acc[3], inv, b0.w);
    res[4] = fmaf(acc[4], inv, b1.x);
    res[5] = fmaf(acc[5], inv, b1.y);
    res[6] = fmaf(acc[6], inv, b1.z);
    res[7] = fmaf(acc[7], inv, b1.w);
    if (MODE == 0) {
        uint4 pk;
        pk.x = (uint)f2bf(res[0]) | ((uint)f2bf(res[1]) << 16);
        pk.y = (uint)f2bf(res[2]) | ((uint)f2bf(res[3]) << 16);
        pk.z = (uint)f2bf(res[4]) | ((uint)f2bf(res[5]) << 16);
        pk.w = (uint)f2bf(res[6]) | ((uint)f2bf(res[7]) << 16);
        *reinterpret_cast<uint4*>((ushort*)outp + ((long)node << 7) + c0) = pk;
    } else {
        // walk this node's output-slot list; write fp32 result to each slot
        const float4 r0 = make_float4(res[0], res[1], res[2], res[3]);
        const float4 r1 = make_float4(res[4], res[5], res[6], res[7]);
        for (int v = hv; v >= 0; v = nextp[v]) {
            float* op = (float*)outp + ((long)v << 7) + c0;
            *reinterpret_cast<float4*>(op)     = r0;
            *reinterpret_cast<float4*>(op + 4) = r1;
        }
    }
}

// ---------------------------------------------------------------------------
extern "C" void kernel_launch(void* const* d_in, const int* in_sizes, int n_in,
                              void* d_out, int out_size, void* d_ws, size_t ws_size,
                              hipStream_t stream)
{
    const float* emb = (const float*)d_in[0];
    const float* W1  = (const float*)d_in[1];
    const float* as1 = (const float*)d_in[2];
    const float* ad1 = (const float*)d_in[3];
    const float* b1  = (const float*)d_in[4];
    const float* W2  = (const float*)d_in[5];
    const float* as2 = (const float*)d_in[6];
    const float* ad2 = (const float*)d_in[7];
    const float* b2  = (const float*)d_in[8];
    const int* edges1 = (const int*)d_in[9];
    const int* edges2 = (const int*)d_in[10];
    const int* idxm   = (const int*)d_in[11];
    float* out = (float*)d_out;

    char* p = (char*)d_ws;
    auto alloc = [&](size_t bytes) {
        char* r = p;
        p += (bytes + 255) & ~(size_t)255;
        return r;
    };
    ushort* hb   = (ushort*)alloc((size_t)N_NODES * C_DIM * 2);  // 25.6 MB
    ushort* a1o  = (ushort*)alloc((size_t)N_NODES * C_DIM * 2);  // 25.6 MB
    uint*   slab = (uint*)alloc((size_t)NBUCK2 * CAP * 4);       // 12.9 MB
    uint*   esrc = (uint*)alloc((size_t)EN2 * 4);                // 7.2 MB (packed)
    int*    offs = (int*)alloc((size_t)(M2 + 1) * 4);
    float*  aS   = (float*)alloc((size_t)N_NODES * 4);
    float*  aD   = (float*)alloc((size_t)N_NODES * 4);
    int*  cursor = (int*)alloc((size_t)NBUCK2 * 4);
    int*  head   = (int*)alloc((size_t)N_NODES * 4);             // init -1
    int*  nextp  = (int*)alloc((size_t)V_OUT * 4);

    // ---- zero cursor; head = -1 (0xFF bytes) -----------------------------
    hipMemsetAsync(cursor, 0, (size_t)NBUCK2 * 4, stream);
    hipMemsetAsync(head, 0xFF, (size_t)N_NODES * 4, stream);

    // ---- CSR build (both layers) + inverse-output-list build -------------
    partition_kernel<<<NCHUNK + VFLAG_BLKS, 256, 0, stream>>>(
        edges1, edges2, cursor, slab, idxm, head, nextp);
    local_csr<<<NBUCK2, 256, 0, stream>>>(slab, cursor, offs, esrc);

    // ---- layer 1 (fp32 emb read + W1 convert fused into gemm staging) ----
    gemm_mfma<1><<<(N_NODES + 63) / 64, 256, 0, stream>>>(emb, W1, as1, ad1, hb, aS, aD);
    aggregate<0><<<N_NODES / 16, 256, 0, stream>>>(hb, aS, aD, b1, offs, esrc, head, nextp, a1o, 0);

    // ---- layer 2 (writes final output directly via inverse list) ---------
    gemm_mfma<0><<<(N_NODES + 63) / 64, 256, 0, stream>>>(a1o, W2, as2, ad2, hb, aS, aD);
    aggregate<1><<<N_NODES / 16, 256, 0, stream>>>(hb, aS, aD, b2, offs, esrc, head, nextp, out, N_NODES);
}

// Round 8
// 259.193 us; speedup vs baseline: 1.0461x; 1.0461x over previous
//
#include <hip/hip_runtime.h>

#define N_NODES 100000
#define C_DIM 128
#define E_EDGES 800000
#define V_OUT 50000
#define EN (E_EDGES + N_NODES)      /* 900000  per-layer CSR entries */
#define M2 (2 * N_NODES)
#define EN2 (2 * EN)                /* 1800000 */

#define BSHIFT 8                    /* 256 nodes per coarse bucket */
#define NBUCK_L ((N_NODES + 255) >> 8)   /* 391 per layer */
#define NBUCK2 (2 * NBUCK_L)             /* 782 */
#define CAP 4096                    /* slab capacity; mean fill 2304, +40 sigma safe */
#define P1_CHUNK 4096
#define P1_PER_T (P1_CHUNK / 256)   /* 16 */
#define NCHUNK ((EN2 + P1_CHUNK - 1) / P1_CHUNK) /* 440 */
#define VFLAG_BLKS ((V_OUT + 255) / 256)         /* 196 */

#define XPAD 136                    /* LDS row stride (ushorts): 272B, 2-way banks */
#define LDS_E 768                   /* staged edges per 16-node block */

#define GEMM_BLKS ((N_NODES + 63) / 64)   /* 1563 */

typedef unsigned int uint;
typedef unsigned short ushort;
typedef __attribute__((ext_vector_type(8))) short bf16x8;
typedef __attribute__((ext_vector_type(4))) float f32x4;

static __device__ __forceinline__ ushort f2bf(float f) {
    uint u = __float_as_uint(f);
    u += 0x7fffu + ((u >> 16) & 1);   // round-to-nearest-even
    return (ushort)(u >> 16);
}

// ---------------------------------------------------------------------------
// GEMM body (streaming-X, 34.8 KB LDS): W fp32->bf16 staged once, A-fragments
// straight from global (coalesced), ws reused as transpose scratch for the
// coalesced hb store. Same code as R7 (measured-neutral = safe).
// ---------------------------------------------------------------------------
template <int IN_F32>
static __device__ __forceinline__ void gemm_body(
    char* smem, int gb, int tid,
    const void* __restrict__ xin, const float* __restrict__ W,
    const float* __restrict__ att_s, const float* __restrict__ att_d,
    ushort* __restrict__ hb, float* __restrict__ a_s, float* __restrict__ a_d)
{
    ushort* ws = (ushort*)smem;       // 128*XPAD ushorts = 34816 B

    // ---- stage W (fp32 -> bf16): thread t -> row t>>1, half t&1 ----------
    {
        const int row = tid >> 1, half = tid & 1;
        const float* src = W + row * 128 + half * 64;
        ushort* dst = &ws[row * XPAD + half * 64];
        #pragma unroll
        for (int i = 0; i < 8; ++i) {
            float4 u = *reinterpret_cast<const float4*>(src + i * 8);
            float4 v = *reinterpret_cast<const float4*>(src + i * 8 + 4);
            uint4 pk;
            pk.x = (uint)f2bf(u.x) | ((uint)f2bf(u.y) << 16);
            pk.y = (uint)f2bf(u.z) | ((uint)f2bf(u.w) << 16);
            pk.z = (uint)f2bf(v.x) | ((uint)f2bf(v.y) << 16);
            pk.w = (uint)f2bf(v.z) | ((uint)f2bf(v.w) << 16);
            *reinterpret_cast<uint4*>(dst + i * 8) = pk;
        }
    }

    const int lane = tid & 63, wv = tid >> 6;
    const int m = lane & 15, quad = lane >> 4;
    const int nb = gb * 64;
    const int n0 = nb + wv * 16;
    const long xrow = min((long)(n0 + m), (long)N_NODES - 1);

    // ---- A-fragments straight from global (coalesced within the wave) ----
    bf16x8 a[4];
    if (IN_F32) {
        const float* src = (const float*)xin + xrow * 128 + quad * 8;
        #pragma unroll
        for (int ki = 0; ki < 4; ++ki) {
            float4 u = *reinterpret_cast<const float4*>(src + ki * 32);
            float4 v = *reinterpret_cast<const float4*>(src + ki * 32 + 4);
            uint4 pk;
            pk.x = (uint)f2bf(u.x) | ((uint)f2bf(u.y) << 16);
            pk.y = (uint)f2bf(u.z) | ((uint)f2bf(u.w) << 16);
            pk.z = (uint)f2bf(v.x) | ((uint)f2bf(v.y) << 16);
            pk.w = (uint)f2bf(v.z) | ((uint)f2bf(v.w) << 16);
            a[ki] = *reinterpret_cast<bf16x8*>(&pk);
        }
    } else {
        const ushort* src = (const ushort*)xin + xrow * 128 + quad * 8;
        #pragma unroll
        for (int ki = 0; ki < 4; ++ki)
            a[ki] = *reinterpret_cast<const bf16x8*>(src + ki * 32);
    }
    __syncthreads();                  // W staged

    // ---- MFMA phase: 8 column-tiles, acc -> packed bf16 in regs ----------
    float ps[4] = {0, 0, 0, 0}, pd[4] = {0, 0, 0, 0};
    uint2 packed[8];
    #pragma unroll
    for (int ct = 0; ct < 8; ++ct) {
        const int cc = ct * 16 + m;
        f32x4 acc = {0.f, 0.f, 0.f, 0.f};
        #pragma unroll
        for (int ki = 0; ki < 4; ++ki) {
            bf16x8 b = *reinterpret_cast<const bf16x8*>(&ws[cc * XPAD + quad * 8 + ki * 32]);
            acc = __builtin_amdgcn_mfma_f32_16x16x32_bf16(a[ki], b, acc, 0, 0, 0);
        }
        const float asc = att_s[cc], adc = att_d[cc];
        #pragma unroll
        for (int r = 0; r < 4; ++r) {
            ps[r] = fmaf(acc[r], asc, ps[r]);
            pd[r] = fmaf(acc[r], adc, pd[r]);
        }
        packed[ct].x = (uint)f2bf(acc[0]) | ((uint)f2bf(acc[1]) << 16);
        packed[ct].y = (uint)f2bf(acc[2]) | ((uint)f2bf(acc[3]) << 16);
    }
    __syncthreads();                  // all ws B-reads done -> ws reusable

    // ---- transpose through ws rows 0..63 ---------------------------------
    {
        const int rowb = (wv * 16 + quad * 4) * XPAD + m;
        #pragma unroll
        for (int ct = 0; ct < 8; ++ct) {
            ws[rowb            + ct * 16] = (ushort)(packed[ct].x);
            ws[rowb +     XPAD + ct * 16] = (ushort)(packed[ct].x >> 16);
            ws[rowb + 2 * XPAD + ct * 16] = (ushort)(packed[ct].y);
            ws[rowb + 3 * XPAD + ct * 16] = (ushort)(packed[ct].y >> 16);
        }
    }
    __syncthreads();                  // transpose complete

    // ---- coalesced hb store: wave covers 4 rows x 256B contiguous --------
    {
        const int sub = tid & 15, rb = tid >> 4;
        #pragma unroll
        for (int i = 0; i < 4; ++i) {
            const int rl = rb + i * 16;
            const int node = nb + rl;
            uint4 v = *reinterpret_cast<const uint4*>(&ws[rl * XPAD + sub * 8]);
            if (node < N_NODES)
                *reinterpret_cast<uint4*>(hb + (long)node * 128 + sub * 8) = v;
        }
    }
    // ---- a_s / a_d shuffle reduce ----------------------------------------
    #pragma unroll
    for (int r = 0; r < 4; ++r) {
        float s = ps[r], d = pd[r];
        #pragma unroll
        for (int x = 1; x < 16; x <<= 1) { s += __shfl_xor(s, x); d += __shfl_xor(d, x); }
        const int node = n0 + quad * 4 + r;
        if (m == 0 && node < N_NODES) { a_s[node] = s; a_d[node] = d; }
    }
}

// ---------------------------------------------------------------------------
// Partition body: edges -> 782 coarse buckets of 256 dst. 6.3 KB of the
// shared scratch (fused kernel reserves 34.8 KB; occupancy set by gemm).
// ---------------------------------------------------------------------------
static __device__ __forceinline__ void partition_body(
    char* smem, int pb, int tid,
    const int* __restrict__ e1, const int* __restrict__ e2,
    int* __restrict__ cursor, uint* __restrict__ slab)
{
    int* cnt     = (int*)smem;        // NBUCK2 = 782 ints
    int* basearr = cnt + NBUCK2;
    for (int i = tid; i < NBUCK2; i += 256) cnt[i] = 0;
    __syncthreads();

    const int e0 = pb * P1_CHUNK;
    uint ent[P1_PER_T];
    int  bkt[P1_PER_T];
    #pragma unroll
    for (int i = 0; i < P1_PER_T; ++i) {
        int e = e0 + i * 256 + tid;
        bkt[i] = -1;
        if (e < EN2) {
            int src, dst, lb;
            if (e < EN) {
                if (e < E_EDGES) { src = e1[e]; dst = e1[E_EDGES + e]; }
                else             { src = dst = e - E_EDGES; }
                lb = 0;
            } else {
                int f = e - EN;
                if (f < E_EDGES) { src = e2[f]; dst = e2[E_EDGES + f]; }
                else             { src = dst = f - E_EDGES; }
                lb = NBUCK_L;
            }
            bkt[i] = lb + (dst >> BSHIFT);
            ent[i] = (uint)src | ((uint)(dst & 255) << 17);
            atomicAdd(&cnt[bkt[i]], 1);
        }
    }
    __syncthreads();
    for (int b = tid; b < NBUCK2; b += 256) {
        int c = cnt[b];
        basearr[b] = (c > 0) ? atomicAdd(&cursor[b], c) : 0;
        cnt[b] = 0;                       // reuse as rank counter
    }
    __syncthreads();
    #pragma unroll
    for (int i = 0; i < P1_PER_T; ++i) {
        if (bkt[i] >= 0) {
            int r = basearr[bkt[i]] + atomicAdd(&cnt[bkt[i]], 1);
            if (r < CAP) slab[(long)bkt[i] * CAP + r] = ent[i];
        }
    }
}

// ---------------------------------------------------------------------------
// Fused front: [gemm layer-1 | edge partition | head-list build], all
// mutually independent. LDS = 34.8 KB uniformly -> gemm keeps its native
// 4 blocks/CU (unlike R2's 52 KB disaster); partition/head blocks backfill.
// head stores v+1 (0 = empty) so head+cursor share one zero-memset.
// ---------------------------------------------------------------------------
__global__ __launch_bounds__(256, 4) void front_kernel(
    const float* __restrict__ emb, const float* __restrict__ W1,
    const float* __restrict__ as1, const float* __restrict__ ad1,
    ushort* __restrict__ hb, float* __restrict__ aS, float* __restrict__ aD,
    const int* __restrict__ e1, const int* __restrict__ e2,
    int* __restrict__ cursor, uint* __restrict__ slab,
    const int* __restrict__ idxm, int* __restrict__ head, int* __restrict__ nextp)
{
    __shared__ __attribute__((aligned(16))) char smem[128 * XPAD * 2];  // 34816 B
    const int b = blockIdx.x;
    const int tid = threadIdx.x;
    if (b < GEMM_BLKS) {
        gemm_body<1>(smem, b, tid, emb, W1, as1, ad1, hb, aS, aD);
    } else if (b < GEMM_BLKS + NCHUNK) {
        partition_body(smem, b - GEMM_BLKS, tid, e1, e2, cursor, slab);
    } else {
        int v = (b - GEMM_BLKS - NCHUNK) * 256 + tid;
        if (v < V_OUT) {
            int n = idxm[v];
            int old = atomicExch(&head[n], v + 1);   // lock-free list push, 0 = empty
            nextp[v] = old;
        }
    }
}

// standalone gemm for layer 2
__global__ __launch_bounds__(256, 4) void gemm2_kernel(
    const ushort* __restrict__ a1o, const float* __restrict__ W2,
    const float* __restrict__ as2, const float* __restrict__ ad2,
    ushort* __restrict__ hb, float* __restrict__ aS, float* __restrict__ aD)
{
    __shared__ __attribute__((aligned(16))) char smem[128 * XPAD * 2];
    gemm_body<0>(smem, blockIdx.x, threadIdx.x, a1o, W2, as2, ad2, hb, aS, aD);
}

// ---------------------------------------------------------------------------
// CSR build, pass 2: one workgroup per 256-node bucket (782 blocks = 2x the
// parallelism of the 512-node version). Inline global prefix of cursor[0..b).
// ---------------------------------------------------------------------------
__global__ __launch_bounds__(256) void local_csr(
    const uint* __restrict__ slab, const int* __restrict__ cursor,
    int* __restrict__ offs, uint* __restrict__ esrc)
{
    __shared__ uint ent[CAP];         // 16 KB
    __shared__ int deg[256];
    __shared__ int excl[256];
    __shared__ int sbase;
    const int b = blockIdx.x;
    const int tid = threadIdx.x;
    const int cnt = min(cursor[b], CAP);
    const int layer = (b >= NBUCK_L);
    const int node0 = (b - layer * NBUCK_L) << BSHIFT;
    const int obase = layer * N_NODES;
    const int nodes_n = min(256, N_NODES - node0);

    if (tid < 256) deg[tid & 255] = 0;
    if (tid < 64) {                   // wave-0: base = sum(cursor[0..b))
        int s = 0;
        #pragma unroll
        for (int k = 0; k < 13; ++k) {
            int idx = tid + 64 * k;
            if (idx < b) s += cursor[idx];
        }
        #pragma unroll
        for (int d = 32; d > 0; d >>= 1) s += __shfl_down(s, d);
        if (tid == 0) sbase = s;
    }
    __syncthreads();
    const int base = sbase;

    for (int i = tid; i < cnt; i += 256) {
        uint v = slab[(long)b * CAP + i];
        ent[i] = v;
        atomicAdd(&deg[v >> 17], 1);
    }
    __syncthreads();
    if (tid < 64) {                   // wave-0 scan of deg[256], 4 per lane
        int v4[4]; int s = 0;
        #pragma unroll
        for (int i = 0; i < 4; ++i) { v4[i] = deg[tid * 4 + i]; s += v4[i]; }
        int incl = s;
        #pragma unroll
        for (int d = 1; d < 64; d <<= 1) {
            int t = __shfl_up(incl, d);
            if (tid >= d) incl += t;
        }
        int e = incl - s;
        #pragma unroll
        for (int i = 0; i < 4; ++i) { excl[tid * 4 + i] = e; e += v4[i]; }
    }
    __syncthreads();
    for (int i = tid; i < nodes_n; i += 256)
        offs[obase + node0 + i] = base + excl[i];
    if (tid < 256) deg[tid & 255] = 0;               // reuse as rank ctr
    if (tid == 0 && node0 + 256 >= N_NODES)
        offs[obase + N_NODES] = base + cnt;          // layer sentinel
    __syncthreads();
    for (int i = tid; i < cnt; i += 256) {
        uint v = ent[i];
        int dl = v >> 17;
        int r = atomicAdd(&deg[dl], 1);
        esrc[base + excl[dl] + r] = v;               // packed src|dl<<17
    }
}

// ---------------------------------------------------------------------------
// Softmax aggregation (phase-2 loop UNCHANGED — the 43.4 us control).
// head semantics: v+1, 0 = empty.
// ---------------------------------------------------------------------------
template <int MODE>
__global__ __launch_bounds__(256) void aggregate(
    const ushort* __restrict__ hb, const float* __restrict__ a_s,
    const float* __restrict__ a_d, const float* __restrict__ bias,
    const int* __restrict__ offs, const uint* __restrict__ esrc,
    const int* __restrict__ head, const int* __restrict__ nextp,
    void* __restrict__ outp, int obase)
{
    __shared__ uint2 ew[LDS_E];       // 6 KB
    const int tid = threadIdx.x;
    const int node0 = blockIdx.x * 16;            // grid = N/16 = 6250
    const int bnode0 = (node0 >> BSHIFT) << BSHIFT;  // bucket's first node (layer-local)
    const int bstart = offs[obase + node0];
    const int bend   = offs[obase + node0 + 16];
    const int nE = bend - bstart;

    // ---- phase 1: stage {v, w} for the block's edges ---------------------
    for (int i = tid; i < min(nE, LDS_E); i += 256) {
        uint v = esrc[bstart + i];
        float w = 0.0f;
        const int d = bnode0 + (v >> 17);
        if (MODE == 0 || head[d] != 0) {
            float e = a_s[v & 0x1ffff] + a_d[d];
            e = (e >= 0.0f) ? e : 0.2f * e;
            w = __expf(e);
        }
        ew[i] = make_uint2(v, __float_as_uint(w));
    }
    __syncthreads();

    // ---- phase 2: slot loop ----------------------------------------------
    const int wave = tid >> 6;
    const int lane = tid & 63;
    const int slot = lane >> 4;
    const int c16  = lane & 15;
    const int node = node0 + wave * 4 + slot;
    int hv = 0;
    if (MODE == 1) {
        hv = head[node];
        if (hv == 0) return;          // uniform across the slot's 16 lanes
    }

    const int start = offs[obase + node];
    const int end   = offs[obase + node + 1];
    const long coff = (long)(c16 << 3);
    float acc[8] = {0, 0, 0, 0, 0, 0, 0, 0};
    float dsum = 0.0f;

    if (start < end) {
        if (nE <= LDS_E) {
            // fast path: per-edge state from LDS, 4-deep h pipeline
            const int jr = start - bstart, jend = end - bstart;
            const int e1 = jend - 1;
            uint2 p0 = ew[jr];
            uint2 p1 = ew[min(jr + 1, e1)];
            uint2 p2 = ew[min(jr + 2, e1)];
            uint2 p3 = ew[min(jr + 3, e1)];
            uint4 h0 = *reinterpret_cast<const uint4*>(hb + ((long)(p0.x & 0x1ffff) << 7) + coff);
            uint4 h1 = *reinterpret_cast<const uint4*>(hb + ((long)(p1.x & 0x1ffff) << 7) + coff);
            uint4 h2 = *reinterpret_cast<const uint4*>(hb + ((long)(p2.x & 0x1ffff) << 7) + coff);
            uint4 h3 = *reinterpret_cast<const uint4*>(hb + ((long)(p3.x & 0x1ffff) << 7) + coff);
            float w0 = __uint_as_float(p0.y);
            float w1 = __uint_as_float(p1.y);
            float w2 = __uint_as_float(p2.y);
            float w3 = __uint_as_float(p3.y);
            for (int j = jr; j < jend; ++j) {
                uint2 p4 = ew[min(j + 4, e1)];
                uint4 h4 = *reinterpret_cast<const uint4*>(hb + ((long)(p4.x & 0x1ffff) << 7) + coff);
                float w4 = __uint_as_float(p4.y);
                dsum += w0;
                acc[0] = fmaf(w0, __uint_as_float(h0.x << 16),         acc[0]);
                acc[1] = fmaf(w0, __uint_as_float(h0.x & 0xffff0000u), acc[1]);
                acc[2] = fmaf(w0, __uint_as_float(h0.y << 16),         acc[2]);
                acc[3] = fmaf(w0, __uint_as_float(h0.y & 0xffff0000u), acc[3]);
                acc[4] = fmaf(w0, __uint_as_float(h0.z << 16),         acc[4]);
                acc[5] = fmaf(w0, __uint_as_float(h0.z & 0xffff0000u), acc[5]);
                acc[6] = fmaf(w0, __uint_as_float(h0.w << 16),         acc[6]);
                acc[7] = fmaf(w0, __uint_as_float(h0.w & 0xffff0000u), acc[7]);
                w0 = w1; w1 = w2; w2 = w3; w3 = w4;
                h0 = h1; h1 = h2; h2 = h3; h3 = h4;
            }
        } else {
            // slow correct path (never taken in practice)
            const float ad = a_d[node];
            for (int j = start; j < end; ++j) {
                uint v = esrc[j];
                float e = a_s[v & 0x1ffff] + ad;
                e = (e >= 0.0f) ? e : 0.2f * e;
                float w = __expf(e);
                uint4 h = *reinterpret_cast<const uint4*>(hb + ((long)(v & 0x1ffff) << 7) + coff);
                dsum += w;
                acc[0] = fmaf(w, __uint_as_float(h.x << 16),         acc[0]);
                acc[1] = fmaf(w, __uint_as_float(h.x & 0xffff0000u), acc[1]);
                acc[2] = fmaf(w, __uint_as_float(h.y << 16),         acc[2]);
                acc[3] = fmaf(w, __uint_as_float(h.y & 0xffff0000u), acc[3]);
                acc[4] = fmaf(w, __uint_as_float(h.z << 16),         acc[4]);
                acc[5] = fmaf(w, __uint_as_float(h.z & 0xffff0000u), acc[5]);
                acc[6] = fmaf(w, __uint_as_float(h.w << 16),         acc[6]);
                acc[7] = fmaf(w, __uint_as_float(h.w & 0xffff0000u), acc[7]);
            }
        }
    }

    const float inv = 1.0f / (dsum + 1e-16f);
    const int c0 = c16 << 3;
    const float4 b0 = *reinterpret_cast<const float4*>(bias + c0);
    const float4 b1 = *reinterpret_cast<const float4*>(bias + c0 + 4);
    float res[8];
    res[0] = fmaf(acc[0], inv, b0.x);
    res[1] = fmaf(acc[1], inv, b0.y);
    res[2] = fmaf(acc[2], inv, b0.z);
    res[3] = fmaf(acc[3], inv, b0.w);
    res[4] = fmaf(acc[4], inv, b1.x);
    res[5] = fmaf(acc[5], inv, b1.y);
    res[6] = fmaf(acc[6], inv, b1.z);
    res[7] = fmaf(acc[7], inv, b1.w);
    if (MODE == 0) {
        uint4 pk;
        pk.x = (uint)f2bf(res[0]) | ((uint)f2bf(res[1]) << 16);
        pk.y = (uint)f2bf(res[2]) | ((uint)f2bf(res[3]) << 16);
        pk.z = (uint)f2bf(res[4]) | ((uint)f2bf(res[5]) << 16);
        pk.w = (uint)f2bf(res[6]) | ((uint)f2bf(res[7]) << 16);
        *reinterpret_cast<uint4*>((ushort*)outp + ((long)node << 7) + c0) = pk;
    } else {
        // walk this node's output-slot list; write fp32 result to each slot
        const float4 r0 = make_float4(res[0], res[1], res[2], res[3]);
        const float4 r1 = make_float4(res[4], res[5], res[6], res[7]);
        for (int v1 = hv; v1 != 0; v1 = nextp[v1 - 1]) {
            float* op = (float*)outp + ((long)(v1 - 1) << 7) + c0;
            *reinterpret_cast<float4*>(op)     = r0;
            *reinterpret_cast<float4*>(op + 4) = r1;
        }
    }
}

// ---------------------------------------------------------------------------
extern "C" void kernel_launch(void* const* d_in, const int* in_sizes, int n_in,
                              void* d_out, int out_size, void* d_ws, size_t ws_size,
                              hipStream_t stream)
{
    const float* emb = (const float*)d_in[0];
    const float* W1  = (const float*)d_in[1];
    const float* as1 = (const float*)d_in[2];
    const float* ad1 = (const float*)d_in[3];
    const float* b1  = (const float*)d_in[4];
    const float* W2  = (const float*)d_in[5];
    const float* as2 = (const float*)d_in[6];
    const float* ad2 = (const float*)d_in[7];
    const float* b2  = (const float*)d_in[8];
    const int* edges1 = (const int*)d_in[9];
    const int* edges2 = (const int*)d_in[10];
    const int* idxm   = (const int*)d_in[11];
    float* out = (float*)d_out;

    char* p = (char*)d_ws;
    auto alloc = [&](size_t bytes) {
        char* r = p;
        p += (bytes + 255) & ~(size_t)255;
        return r;
    };
    ushort* hb   = (ushort*)alloc((size_t)N_NODES * C_DIM * 2);  // 25.6 MB
    ushort* a1o  = (ushort*)alloc((size_t)N_NODES * C_DIM * 2);  // 25.6 MB
    uint*   slab = (uint*)alloc((size_t)NBUCK2 * CAP * 4);       // 12.8 MB
    uint*   esrc = (uint*)alloc((size_t)EN2 * 4);                // 7.2 MB (packed)
    int*    offs = (int*)alloc((size_t)(M2 + 1) * 4);
    float*  aS   = (float*)alloc((size_t)N_NODES * 4);
    float*  aD   = (float*)alloc((size_t)N_NODES * 4);
    int*  nextp  = (int*)alloc((size_t)V_OUT * 4);
    // cursor + head contiguous, both zero-init -> ONE memset
    int*  cursor = (int*)alloc((size_t)NBUCK2 * 4);
    int*  head   = (int*)alloc((size_t)N_NODES * 4);             // v+1, 0 = empty

    hipMemsetAsync(cursor, 0,
                   (size_t)((char*)head - (char*)cursor) + (size_t)N_NODES * 4, stream);

    // ---- fused front: gemm1 | partition | head-list ----------------------
    front_kernel<<<GEMM_BLKS + NCHUNK + VFLAG_BLKS, 256, 0, stream>>>(
        emb, W1, as1, ad1, hb, aS, aD, edges1, edges2, cursor, slab,
        idxm, head, nextp);

    // ---- CSR pass 2 ------------------------------------------------------
    local_csr<<<NBUCK2, 256, 0, stream>>>(slab, cursor, offs, esrc);

    // ---- layer 1 aggregate -----------------------------------------------
    aggregate<0><<<N_NODES / 16, 256, 0, stream>>>(hb, aS, aD, b1, offs, esrc, head, nextp, a1o, 0);

    // ---- layer 2 ---------------------------------------------------------
    gemm2_kernel<<<GEMM_BLKS, 256, 0, stream>>>(a1o, W2, as2, ad2, hb, aS, aD);
    aggregate<1><<<N_NODES / 16, 256, 0, stream>>>(hb, aS, aD, b2, offs, esrc, head, nextp, out, N_NODES);
}